// Round 2
// baseline (2512.869 us; speedup 1.0000x reference)
//
#include <hip/hip_runtime.h>
#include <hip/hip_bf16.h>
#include <cmath>

// Problem constants (from reference setup_inputs)
#define B       64
#define IN_PN   20000
#define OUT_PN  5000
#define MM      9
#define CIN     32
#define COUT    64
#define XS      68   // k-major tile stride (floats): 64 + 4 pad, float4-aligned

// One block per output point p. 256 threads = 4 waves.
// LDS tiles are k-major: Xs[k][b], Ws[k][o] (stride 68).
// Compute map: 16x16 thread grid, thread (i,j) owns C[4i:4i+4][4j:4j+4]
//   -> per k: 1 ds_read_b128 (X) + 1 ds_read_b128 (W) -> 16 v_fmac.
// Register footprint ~55 VGPRs: no spills (R1 failure mode: 3.65 GB spill writes).
__global__ __launch_bounds__(256, 4) void pconv_kernel(
    const float* __restrict__ in_pc,       // (B, IN_PN, CIN)
    const int*   __restrict__ neighbor_id, // (OUT_PN, M)
    const float* __restrict__ weights,     // (OUT_PN, M, COUT, CIN)
    const float* __restrict__ bias,        // (OUT_PN, COUT)
    const float* __restrict__ p_neighbors, // (OUT_PN, M)
    const float* __restrict__ weight_res,  // (COUT, CIN)
    float*       __restrict__ out)         // (B, OUT_PN, COUT)
{
    __shared__ float Xs[CIN * XS];  // [k][b]  2176 floats
    __shared__ float Ws[CIN * XS];  // [k][o]  2176 floats

    const int p  = blockIdx.x;
    const int t  = threadIdx.x;
    const int j4 = (t & 15) * 4;    // output-col base (o)
    const int i4 = (t >> 4) * 4;    // batch-row base (b)
    const int bb = t >> 2;          // X staging: batch row
    const int q4 = (t & 3) * 4;     // X staging: c base within half-row
    const int wo = t >> 3;          // W staging: o (first half)
    const int wc = (t & 7) * 4;     // W staging: c base

    // ---- neighbor ids + normalized residual weights (block-uniform -> s_load) ----
    int   nid[MM];
    float pn[MM];
    float psum = 0.f;
#pragma unroll
    for (int m = 0; m < MM; ++m) {
        nid[m] = neighbor_id[p * MM + m];
        float pv = fabsf(p_neighbors[p * MM + m]);
        pv = (nid[m] != IN_PN) ? pv : 0.f;
        pn[m] = pv;
        psum += pv;
    }
    const float pinv = 1.f / (psum + 1e-8f);
#pragma unroll
    for (int m = 0; m < MM; ++m) pn[m] *= pinv;

    float acc[16];
#pragma unroll
    for (int v = 0; v < 16; ++v) acc[v] = 0.f;
    float rv[8];   // residual R[bb][q4..q4+3], R[bb][16+q4..] accumulated in staging regs
#pragma unroll
    for (int v = 0; v < 8; ++v) rv[v] = 0.f;

    for (int m = 0; m < MM; ++m) {
        // ---- stage X (gather; n is block-uniform) ----
        const int n = nid[m];
        float4 a0 = make_float4(0.f, 0.f, 0.f, 0.f), a1 = a0;
        if (n != IN_PN) {
            const float* src = in_pc + ((size_t)bb * IN_PN + (size_t)n) * CIN;
            a0 = *(const float4*)(src + q4);
            a1 = *(const float4*)(src + 16 + q4);
        }
        const float* ax0 = &a0.x;
        const float* ax1 = &a1.x;
        const float pm = pn[m];
#pragma unroll
        for (int u = 0; u < 4; ++u) {
            Xs[(q4 + u) * XS + bb]      = ax0[u];
            Xs[(16 + q4 + u) * XS + bb] = ax1[u];
            rv[u]     += pm * ax0[u];   // residual rides on staging regs
            rv[4 + u] += pm * ax1[u];
        }

        // ---- stage W transposed to k-major ----
        const float* wsrc = weights + ((size_t)p * MM + m) * (COUT * CIN);
        float4 w0 = *(const float4*)(wsrc + t * 4);          // o = t>>3,     c = wc..wc+3
        float4 w1 = *(const float4*)(wsrc + 1024 + t * 4);   // o = 32+(t>>3), c same
        const float* wx0 = &w0.x;
        const float* wx1 = &w1.x;
#pragma unroll
        for (int u = 0; u < 4; ++u) {
            Ws[(wc + u) * XS + wo]      = wx0[u];
            Ws[(wc + u) * XS + 32 + wo] = wx1[u];
        }
        __syncthreads();

        // ---- 64x64x32 FMA tile, 4x4 per thread ----
#pragma unroll
        for (int k = 0; k < CIN; ++k) {
            float4 xa = *(const float4*)&Xs[k * XS + i4];
            float4 wv = *(const float4*)&Ws[k * XS + j4];
            acc[0]  += xa.x * wv.x;  acc[1]  += xa.x * wv.y;  acc[2]  += xa.x * wv.z;  acc[3]  += xa.x * wv.w;
            acc[4]  += xa.y * wv.x;  acc[5]  += xa.y * wv.y;  acc[6]  += xa.y * wv.z;  acc[7]  += xa.y * wv.w;
            acc[8]  += xa.z * wv.x;  acc[9]  += xa.z * wv.y;  acc[10] += xa.z * wv.z;  acc[11] += xa.z * wv.w;
            acc[12] += xa.w * wv.x;  acc[13] += xa.w * wv.y;  acc[14] += xa.w * wv.z;  acc[15] += xa.w * wv.w;
        }
        __syncthreads();
    }

    // ---- residual GEMM: R(64x32) . weight_res(64x32)^T, same tile structure ----
#pragma unroll
    for (int u = 0; u < 4; ++u) {
        Xs[(q4 + u) * XS + bb]      = rv[u];
        Xs[(16 + q4 + u) * XS + bb] = rv[4 + u];
    }
    {
        float4 w0 = *(const float4*)(weight_res + t * 4);
        float4 w1 = *(const float4*)(weight_res + 1024 + t * 4);
        const float* wx0 = &w0.x;
        const float* wx1 = &w1.x;
#pragma unroll
        for (int u = 0; u < 4; ++u) {
            Ws[(wc + u) * XS + wo]      = wx0[u];
            Ws[(wc + u) * XS + 32 + wo] = wx1[u];
        }
    }
    __syncthreads();

    float racc[16];
#pragma unroll
    for (int v = 0; v < 16; ++v) racc[v] = 0.f;
#pragma unroll
    for (int k = 0; k < CIN; ++k) {
        float4 xa = *(const float4*)&Xs[k * XS + i4];
        float4 wv = *(const float4*)&Ws[k * XS + j4];
        racc[0]  += xa.x * wv.x;  racc[1]  += xa.x * wv.y;  racc[2]  += xa.x * wv.z;  racc[3]  += xa.x * wv.w;
        racc[4]  += xa.y * wv.x;  racc[5]  += xa.y * wv.y;  racc[6]  += xa.y * wv.z;  racc[7]  += xa.y * wv.w;
        racc[8]  += xa.z * wv.x;  racc[9]  += xa.z * wv.y;  racc[10] += xa.z * wv.z;  racc[11] += xa.z * wv.w;
        racc[12] += xa.w * wv.x;  racc[13] += xa.w * wv.y;  racc[14] += xa.w * wv.z;  racc[15] += xa.w * wv.w;
    }

    // ---- epilogue: elu(conv+bias)*s + res*s, direct coalesced stores ----
    float4 bias4 = *(const float4*)(bias + p * COUT + j4);
    const float* bx = &bias4.x;
#pragma unroll
    for (int r = 0; r < 4; ++r) {
        float4 v;
        float* vx = &v.x;
#pragma unroll
        for (int s = 0; s < 4; ++s) {
            float cv = acc[r * 4 + s] + bx[s];
            cv = (cv > 0.f) ? cv : expm1f(cv);   // jax.nn.elu
            vx[s] = 0.70710678118654752f * (cv + racc[r * 4 + s]);  // sqrt(1-RR)=sqrt(RR)
        }
        *(float4*)&out[((size_t)(i4 + r) * OUT_PN + (size_t)p) * COUT + j4] = v;
    }
}

extern "C" void kernel_launch(void* const* d_in, const int* in_sizes, int n_in,
                              void* d_out, int out_size, void* d_ws, size_t ws_size,
                              hipStream_t stream) {
    const float* in_pc       = (const float*)d_in[0];
    const int*   neighbor_id = (const int*)d_in[1];
    const float* weights     = (const float*)d_in[2];
    const float* bias        = (const float*)d_in[3];
    const float* p_neighbors = (const float*)d_in[4];
    const float* weight_res  = (const float*)d_in[5];
    float*       out         = (float*)d_out;

    pconv_kernel<<<OUT_PN, 256, 0, stream>>>(in_pc, neighbor_id, weights, bias,
                                             p_neighbors, weight_res, out);
}